// Round 12
// baseline (846.974 us; speedup 1.0000x reference)
//
#include <hip/hip_runtime.h>
#include <stdint.h>

// WeightOnlyInt4Linear: y = X @ dequant(Q)^T ; M=8192, K=4096, N=11008, G=128.
// Round 12: r10's proven ring + 32x32x16 MFMA (2382 TF pipe vs 2075, half the
// MFMA instructions). Same LDS image, same staging, same swizzle; reads are
// (ks*2+g)^(row&7) slots; C/D map col=lane&31, row=(reg&3)+8*(reg>>2)+4*(lane>>5).

typedef __attribute__((ext_vector_type(8))) short short8;
typedef __attribute__((ext_vector_type(16))) float float16v;
typedef __attribute__((ext_vector_type(4))) float float4v;
typedef __attribute__((ext_vector_type(4))) int int4v;
typedef __attribute__((ext_vector_type(2))) float float2v;
typedef __attribute__((ext_vector_type(4))) unsigned short ushort4v;

static constexpr int M_ = 8192;
static constexpr int K_ = 4096;
static constexpr int N_ = 11008;
static constexpr int NKT = K_ / 64;  // 64 K-tiles

__device__ __forceinline__ unsigned short f2bf(float f) {
    union { float f; uint32_t u; } v;
    v.f = f;
    uint32_t u = v.u;
    u += 0x7fffu + ((u >> 16) & 1u);  // RNE
    return (unsigned short)(u >> 16);
}

__device__ __forceinline__ void gload16(const void* g, void* l) {
    __builtin_amdgcn_global_load_lds(
        (const __attribute__((address_space(1))) uint32_t*)g,
        (__attribute__((address_space(3))) uint32_t*)l, 16, 0, 0);
}

// ---------------- Prepass 1: X fp32 -> bf16 ----------------
__global__ __launch_bounds__(256) void cvt_x_kernel(const float* __restrict__ X,
                                                    unsigned short* __restrict__ Xb) {
    const int i = blockIdx.x * 256 + threadIdx.x;
    const float4v a = ((const float4v*)X)[2 * (size_t)i];
    const float4v b = ((const float4v*)X)[2 * (size_t)i + 1];
    short8 o;
    #pragma unroll
    for (int j = 0; j < 4; ++j) o[j] = (short)f2bf(a[j]);
    #pragma unroll
    for (int j = 0; j < 4; ++j) o[4 + j] = (short)f2bf(b[j]);
    ((short8*)Xb)[(size_t)i] = o;
}

// ---------------- Prepass 2: W int4 codes -> bf16 ----------------
__global__ __launch_bounds__(256) void deq_w_kernel(const int* __restrict__ Q,
                                                    const float* __restrict__ SZ,
                                                    unsigned short* __restrict__ Wb) {
    const int i = blockIdx.x * 256 + threadIdx.x;  // < N*K/8
    const int n = i >> 9;
    const int c = i & 511;
    const int k0 = c * 8;
    const int g = k0 >> 7;
    const float2v sz = *(const float2v*)(SZ + ((size_t)g * N_ + n) * 2);
    const float s = sz[0], z = sz[1];
    const int4v q0 = *(const int4v*)(Q + (size_t)n * K_ + k0);
    const int4v q1 = *(const int4v*)(Q + (size_t)n * K_ + k0 + 4);
    short8 o;
    #pragma unroll
    for (int j = 0; j < 4; ++j) o[j] = (short)f2bf((float)(q0[j] - 8) * s + z);
    #pragma unroll
    for (int j = 0; j < 4; ++j) o[4 + j] = (short)f2bf((float)(q1[j] - 8) * s + z);
    ((short8*)Wb)[(size_t)i] = o;
}

// ---------------- 256x256 GEMM, 32x32x16 MFMA, r10 ring ----------------
// LDS (bytes): A buf0 [0,32K) A buf1 [32K,64K) B buf0 [64K,96K) B buf1 [96K,128K)
// Tile: 256 rows x 64 bf16 (128 B/row); half = 128 rows = 16 KB.
// LDS[row][slot(16B)] holds global k-chunk (slot ^ (row&7)).

#define SBAR() __builtin_amdgcn_sched_barrier(0)
#define VMW(n) asm volatile("s_waitcnt vmcnt(" #n ")" ::: "memory")
#define LGKM(n) asm volatile("s_waitcnt lgkmcnt(" #n ")" ::: "memory")
#define BARRIER() __builtin_amdgcn_s_barrier()

__global__ __launch_bounds__(512, 2) void gemm_bf16_8ph(
    const unsigned short* __restrict__ Agl,  // [M][K] bf16
    const unsigned short* __restrict__ Bgl,  // [N][K] bf16
    float* __restrict__ C) {
    __shared__ alignas(16) unsigned short lds[65536];  // 128 KiB

    const int tid = threadIdx.x;
    const int lane = tid & 63;
    const int wid = tid >> 6;   // 0..7
    const int wr = wid >> 2;    // 0..1 (M sub-block within half)
    const int wc = wid & 3;     // 0..3 (N sub-block within half)

    // T1: XCD swizzle over 1376 = 8*172 blocks.
    const int bid = blockIdx.x;
    const int wg = (bid & 7) * 172 + (bid >> 3);
    const int mt = wg / 43;
    const int nt = wg % 43;
    const int row0 = mt * 256;
    const int col0 = nt * 256;

    // staging lane geometry: wave writes 8 rows x 128 B linear.
    const int r8 = lane >> 3;                // 0..7 == row&7
    const int kc = ((lane & 7) ^ r8) * 8;    // inverse-swizzled global k-elem offset

    // 32x32x16 read lane geometry: row = lane&31, kgroup g = lane>>5.
    const int l31 = lane & 31;
    const int g5 = lane >> 5;
    // slot(ks) = (ks*2 + g5) ^ (lane&7); byte = slot*16
    int aO[4], bO[4];
    #pragma unroll
    for (int ks = 0; ks < 4; ++ks) {
        const int ko = (((ks * 2 + g5) ^ (lane & 7)) << 4);
        aO[ks] = wr * 8192 + l31 * 128 + ko;
        bO[ks] = 65536 + wc * 4096 + l31 * 128 + ko;
    }
    const char* ldsB = (const char*)lds;
    unsigned short* ldsU = lds;
    const char* AglB = (const char*)Agl;
    const char* BglB = (const char*)Bgl;

    // Persistent 32-bit staging byte-offsets, one per stream [h][i]; +128 B/use.
    uint32_t sA[2][2], sB[2][2];
    #pragma unroll
    for (int h = 0; h < 2; ++h)
        #pragma unroll
        for (int i = 0; i < 2; ++i) {
            sA[h][i] = (uint32_t)(row0 + h * 128 + (wid * 2 + i) * 8 + r8) * (K_ * 2)
                       + (uint32_t)kc * 2;
            sB[h][i] = (uint32_t)(col0 + h * 128 + (wid * 2 + i) * 8 + r8) * (K_ * 2)
                       + (uint32_t)kc * 2;
        }

    auto gA = [&](uint32_t& off, int b, int h, int i) {
        gload16(AglB + off, ldsU + b * 16384 + (h * 128 + (wid * 2 + i) * 8) * 64);
        off += 128;
    };
    auto gB = [&](uint32_t& off, int b, int h, int i) {
        gload16(BglB + off, ldsU + 32768 + b * 16384 + (h * 128 + (wid * 2 + i) * 8) * 64);
        off += 128;
    };

    float16v acc[4][2] = {};  // [mf][nf]: mf -> rows (mf>>1)*128 + wr*64 + (mf&1)*32

// A-fragment read: quadrant half MH, sub-tile MI, k-step KS (one ds_read_b128)
#define RDA(DST, CB, MH, MI, KS) \
    DST[MI][KS] = *(const short8*)(ldsB + (CB) + (MH)*16384 + (MI)*4096 + aO[KS]);
// B-fragment read: half NH, k-step KS (bO carries the +64K B-region bias)
#define RDB(DST, CB, NH, KS) \
    DST[KS] = *(const short8*)(ldsB + (CB) + (NH)*16384 + bO[KS]);
// 4 MFMA (k-steps 0-3) accumulating acc[MF][NF] from A[MI][*], B[*]
#define MMA4(MF, NF, A, MI, B)                                              \
    acc[MF][NF] = __builtin_amdgcn_mfma_f32_32x32x16_bf16(A[MI][0], B[0], acc[MF][NF], 0, 0, 0); \
    acc[MF][NF] = __builtin_amdgcn_mfma_f32_32x32x16_bf16(A[MI][1], B[1], acc[MF][NF], 0, 0, 0); \
    acc[MF][NF] = __builtin_amdgcn_mfma_f32_32x32x16_bf16(A[MI][2], B[2], acc[MF][NF], 0, 0, 0); \
    acc[MF][NF] = __builtin_amdgcn_mfma_f32_32x32x16_bf16(A[MI][3], B[3], acc[MF][NF], 0, 0, 0);

    // Prologue: stage tile 0 -> buf0, order [A0, B0, B1, A1]; VMW(4) drains A0,B0.
    gA(sA[0][0], 0, 0, 0); gA(sA[0][1], 0, 0, 1);
    gB(sB[0][0], 0, 0, 0); gB(sB[0][1], 0, 0, 1);
    gB(sB[1][0], 0, 1, 0); gB(sB[1][1], 0, 1, 1);
    gA(sA[1][0], 0, 1, 0); gA(sA[1][1], 0, 1, 1);
    VMW(4);
    BARRIER(); SBAR();

    // Per tile (BUF): P1 <MH0,NH0> reads A-h0(8)+B-h0(4), stages A0'(t+1);
    // P2 <MH0,NH1> reads B-h1(4), stages B0'; P3 <MH1,NH0> reads A-h1(8),
    // stages B1'; P4 <MH1,NH1> no reads, stages A1'. vmcnt: 4->6->VMW(4) at
    // P1/P2/P4 ends drains exactly the pair the next consumer needs; tail 2/0.
#define KTILE(BUF, DN, W1, W2, W3, DOEND)                                   \
    {                                                                       \
        constexpr int CB = (BUF) * 32768;                                   \
        short8 a01[2][4], a23[2][4], b0[4], b1[4];                          \
        /* P1: read A-h0, B-h0 ; stage A0(t+1) */                           \
        RDA(a01, CB, 0, 0, 0) RDA(a01, CB, 0, 0, 1)                         \
        RDA(a01, CB, 0, 0, 2) RDA(a01, CB, 0, 0, 3)                         \
        RDA(a01, CB, 0, 1, 0) RDA(a01, CB, 0, 1, 1)                         \
        RDA(a01, CB, 0, 1, 2) RDA(a01, CB, 0, 1, 3)                         \
        RDB(b0, CB, 0, 0) RDB(b0, CB, 0, 1) RDB(b0, CB, 0, 2) RDB(b0, CB, 0, 3) \
        if (DN) { gA(sA[0][0], (BUF) ^ 1, 0, 0); gA(sA[0][1], (BUF) ^ 1, 0, 1); } \
        LGKM(8);                                                            \
        BARRIER(); SBAR();                                                  \
        LGKM(0); SBAR();                                                    \
        __builtin_amdgcn_s_setprio(1);                                      \
        MMA4(0, 0, a01, 0, b0) MMA4(1, 0, a01, 1, b0)                       \
        __builtin_amdgcn_s_setprio(0);                                      \
        VMW(W1);                                                            \
        BARRIER(); SBAR();                                                  \
        /* P2: read B-h1 ; stage B0(t+1) */                                 \
        RDB(b1, CB, 1, 0) RDB(b1, CB, 1, 1) RDB(b1, CB, 1, 2) RDB(b1, CB, 1, 3) \
        if (DN) { gB(sB[0][0], (BUF) ^ 1, 0, 0); gB(sB[0][1], (BUF) ^ 1, 0, 1); } \
        BARRIER(); SBAR();                                                  \
        LGKM(0); SBAR();                                                    \
        __builtin_amdgcn_s_setprio(1);                                      \
        MMA4(0, 1, a01, 0, b1) MMA4(1, 1, a01, 1, b1)                       \
        __builtin_amdgcn_s_setprio(0);                                      \
        VMW(W2);                                                            \
        BARRIER(); SBAR();                                                  \
        /* P3: read A-h1 ; stage B1(t+1) */                                 \
        RDA(a23, CB, 1, 0, 0) RDA(a23, CB, 1, 0, 1)                         \
        RDA(a23, CB, 1, 0, 2) RDA(a23, CB, 1, 0, 3)                         \
        RDA(a23, CB, 1, 1, 0) RDA(a23, CB, 1, 1, 1)                         \
        RDA(a23, CB, 1, 1, 2) RDA(a23, CB, 1, 1, 3)                         \
        if (DN) { gB(sB[1][0], (BUF) ^ 1, 1, 0); gB(sB[1][1], (BUF) ^ 1, 1, 1); } \
        BARRIER(); SBAR();                                                  \
        LGKM(0); SBAR();                                                    \
        __builtin_amdgcn_s_setprio(1);                                      \
        MMA4(2, 0, a23, 0, b0) MMA4(3, 0, a23, 1, b0)                       \
        __builtin_amdgcn_s_setprio(0);                                      \
        BARRIER(); SBAR();                                                  \
        /* P4: no reads ; stage A1(t+1) */                                  \
        if (DN) { gA(sA[1][0], (BUF) ^ 1, 1, 0); gA(sA[1][1], (BUF) ^ 1, 1, 1); } \
        __builtin_amdgcn_s_setprio(1);                                      \
        MMA4(2, 1, a23, 0, b1) MMA4(3, 1, a23, 1, b1)                       \
        __builtin_amdgcn_s_setprio(0);                                      \
        if (DOEND) {                                                        \
            VMW(W3);                                                        \
            BARRIER(); SBAR();                                              \
        }                                                                   \
    }

    for (int t2 = 0; t2 < NKT - 2; t2 += 2) {
        KTILE(0, 1, 4, 4, 4, 1);
        KTILE(1, 1, 4, 4, 4, 1);
    }
    KTILE(0, 1, 4, 4, 4, 1);  // tile NKT-2: stages tile NKT-1 normally
    KTILE(1, 0, 2, 0, 0, 0);  // tile NKT-1: no stages; VMW 2/0; no end sync
#undef KTILE
#undef RDA
#undef RDB
#undef MMA4

    // Epilogue: 32x32 D map col=lane&31, row=(reg&3)+8*(reg>>2)+4*(lane>>5)
    // (m74/m101-verified).
    #pragma unroll
    for (int mf = 0; mf < 4; ++mf)
        #pragma unroll
        for (int nf = 0; nf < 2; ++nf) {
            const int rbase = row0 + (mf >> 1) * 128 + wr * 64 + (mf & 1) * 32 + 4 * g5;
            const int c = col0 + nf * 128 + wc * 32 + l31;
            #pragma unroll
            for (int reg = 0; reg < 16; ++reg) {
                const int r = rbase + (reg & 3) + 8 * (reg >> 2);
                C[(size_t)r * N_ + c] = acc[mf][nf][reg];
            }
        }
}

// ---------------- Fallback: round-1 fused kernel ----------------
static constexpr int LDSS = 40;

__global__ __launch_bounds__(256, 2) void w4_gemm_fused(
    const float* __restrict__ X, const int* __restrict__ Q,
    const float* __restrict__ SZ, float* __restrict__ C) {
    __shared__ alignas(16) unsigned short As[128 * LDSS];
    __shared__ alignas(16) unsigned short Ws[128 * LDSS];
    const int tid = threadIdx.x;
    const int lane = tid & 63;
    const int wid = tid >> 6;
    const int wrr = wid >> 1;
    const int wcc = wid & 1;
    const int row0 = blockIdx.x * 128;
    const int col0 = blockIdx.y * 128;
    float4v acc[4][4] = {};
    float4v a_reg[4];
    int4v q_reg[4];
    float2v sz_reg[4];

    auto load_tile = [&](int kb) {
        const int g = kb >> 7;
        #pragma unroll
        for (int i = 0; i < 4; ++i) {
            const int idx = tid + 256 * i;
            const int r = idx >> 3;
            const int v = idx & 7;
            a_reg[i] = *(const float4v*)(X + (size_t)(row0 + r) * K_ + kb + v * 4);
            q_reg[i] = *(const int4v*)(Q + (size_t)(col0 + r) * K_ + kb + v * 4);
            sz_reg[i] = *(const float2v*)(SZ + ((size_t)g * N_ + (col0 + r)) * 2);
        }
    };
    auto write_tile = [&]() {
        #pragma unroll
        for (int i = 0; i < 4; ++i) {
            const int idx = tid + 256 * i;
            const int r = idx >> 3;
            const int v = idx & 7;
            ushort4v ab, wb;
            #pragma unroll
            for (int j = 0; j < 4; ++j) ab[j] = f2bf(a_reg[i][j]);
            const float s = sz_reg[i][0];
            const float z = sz_reg[i][1];
            #pragma unroll
            for (int j = 0; j < 4; ++j) wb[j] = f2bf((float)(q_reg[i][j] - 8) * s + z);
            *(ushort4v*)(&As[r * LDSS + v * 4]) = ab;
            *(ushort4v*)(&Ws[r * LDSS + v * 4]) = wb;
        }
    };
    auto compute = [&]() {
        const int lr = lane & 15;
        const int lg = lane >> 4;
        short8 af[4], bf[4];
        #pragma unroll
        for (int mf = 0; mf < 4; ++mf)
            af[mf] = *(const short8*)(&As[(wrr * 64 + mf * 16 + lr) * LDSS + lg * 8]);
        #pragma unroll
        for (int nf = 0; nf < 4; ++nf)
            bf[nf] = *(const short8*)(&Ws[(wcc * 64 + nf * 16 + lr) * LDSS + lg * 8]);
        #pragma unroll
        for (int mf = 0; mf < 4; ++mf)
            #pragma unroll
            for (int nf = 0; nf < 4; ++nf)
                acc[mf][nf] = __builtin_amdgcn_mfma_f32_16x16x32_bf16(
                    af[mf], bf[nf], acc[mf][nf], 0, 0, 0);
    };

    load_tile(0);
    for (int kb = 0; kb < K_; kb += 32) {
        __syncthreads();
        write_tile();
        __syncthreads();
        if (kb + 32 < K_) load_tile(kb + 32);
        compute();
    }
    const int lr = lane & 15;
    const int lg = lane >> 4;
    #pragma unroll
    for (int mf = 0; mf < 4; ++mf)
        #pragma unroll
        for (int nf = 0; nf < 4; ++nf)
            #pragma unroll
            for (int j = 0; j < 4; ++j) {
                const int r = row0 + wrr * 64 + mf * 16 + lg * 4 + j;
                const int c = col0 + wcc * 64 + nf * 16 + lr;
                C[(size_t)r * N_ + c] = acc[mf][nf][j];
            }
}

extern "C" void kernel_launch(void* const* d_in, const int* in_sizes, int n_in,
                              void* d_out, int out_size, void* d_ws, size_t ws_size,
                              hipStream_t stream) {
    const float* X  = (const float*)d_in[0];
    const int*   Q  = (const int*)d_in[1];
    const float* SZ = (const float*)d_in[2];
    float* C = (float*)d_out;

    const size_t xb_bytes = (size_t)M_ * K_ * 2;
    const size_t wb_bytes = (size_t)N_ * K_ * 2;
    if (ws_size >= xb_bytes + wb_bytes) {
        unsigned short* Xb = (unsigned short*)d_ws;
        unsigned short* Wb = (unsigned short*)((char*)d_ws + xb_bytes);
        cvt_x_kernel<<<(M_ * (K_ / 8)) / 256, 256, 0, stream>>>(X, Xb);
        deq_w_kernel<<<(N_ * (K_ / 8)) / 256, 256, 0, stream>>>(Q, SZ, Wb);
        gemm_bf16_8ph<<<dim3(1376), dim3(512), 0, stream>>>(Xb, Wb, C);
    } else {
        dim3 grid(M_ / 128, N_ / 128);
        w4_gemm_fused<<<grid, dim3(256), 0, stream>>>(X, Q, SZ, C);
    }
}

// Round 13
// 740.275 us; speedup vs baseline: 1.1441x; 1.1441x over previous
//
#include <hip/hip_runtime.h>
#include <stdint.h>

// WeightOnlyInt4Linear: y = X @ dequant(Q)^T ; M=8192, K=4096, N=11008, G=128.
// Round 13: r11 pipeline + T19 sched_group_barrier pinning. Diagnosis: LLVM
// re-clusters ds_reads within each sched region, defeating the textual
// mma/read interleave -> alternating pipes (sum). SGB forces the emitted
// order {4 MFMA, 1 ds_read}xN so reads issue in MFMA-pipe gaps.
// Ring (proven r9/r10/r11): S1={A1',B0'}@P1, S2={B1'}@P2, S3={A0''->BUF}@mid;
// MID=VMW(4)+BAR, END=VMW(2)+BAR; tail 2/0. Swizzle: byte ^= (row&7)<<4.

typedef __attribute__((ext_vector_type(8))) short short8;
typedef __attribute__((ext_vector_type(4))) float float4v;
typedef __attribute__((ext_vector_type(4))) int int4v;
typedef __attribute__((ext_vector_type(2))) float float2v;
typedef __attribute__((ext_vector_type(4))) unsigned short ushort4v;

static constexpr int M_ = 8192;
static constexpr int K_ = 4096;
static constexpr int N_ = 11008;
static constexpr int NKT = K_ / 64;  // 64 K-tiles

__device__ __forceinline__ unsigned short f2bf(float f) {
    union { float f; uint32_t u; } v;
    v.f = f;
    uint32_t u = v.u;
    u += 0x7fffu + ((u >> 16) & 1u);  // RNE
    return (unsigned short)(u >> 16);
}

__device__ __forceinline__ void gload16(const void* g, void* l) {
    __builtin_amdgcn_global_load_lds(
        (const __attribute__((address_space(1))) uint32_t*)g,
        (__attribute__((address_space(3))) uint32_t*)l, 16, 0, 0);
}

// ---------------- Prepass 1: X fp32 -> bf16 ----------------
__global__ __launch_bounds__(256) void cvt_x_kernel(const float* __restrict__ X,
                                                    unsigned short* __restrict__ Xb) {
    const int i = blockIdx.x * 256 + threadIdx.x;
    const float4v a = ((const float4v*)X)[2 * (size_t)i];
    const float4v b = ((const float4v*)X)[2 * (size_t)i + 1];
    short8 o;
    #pragma unroll
    for (int j = 0; j < 4; ++j) o[j] = (short)f2bf(a[j]);
    #pragma unroll
    for (int j = 0; j < 4; ++j) o[4 + j] = (short)f2bf(b[j]);
    ((short8*)Xb)[(size_t)i] = o;
}

// ---------------- Prepass 2: W int4 codes -> bf16 ----------------
__global__ __launch_bounds__(256) void deq_w_kernel(const int* __restrict__ Q,
                                                    const float* __restrict__ SZ,
                                                    unsigned short* __restrict__ Wb) {
    const int i = blockIdx.x * 256 + threadIdx.x;  // < N*K/8
    const int n = i >> 9;
    const int c = i & 511;
    const int k0 = c * 8;
    const int g = k0 >> 7;
    const float2v sz = *(const float2v*)(SZ + ((size_t)g * N_ + n) * 2);
    const float s = sz[0], z = sz[1];
    const int4v q0 = *(const int4v*)(Q + (size_t)n * K_ + k0);
    const int4v q1 = *(const int4v*)(Q + (size_t)n * K_ + k0 + 4);
    short8 o;
    #pragma unroll
    for (int j = 0; j < 4; ++j) o[j] = (short)f2bf((float)(q0[j] - 8) * s + z);
    #pragma unroll
    for (int j = 0; j < 4; ++j) o[4 + j] = (short)f2bf((float)(q1[j] - 8) * s + z);
    ((short8*)Wb)[(size_t)i] = o;
}

// ---------------- 256x256 GEMM, SGB-pinned interleave ----------------
// LDS (bytes): A buf0 [0,32K) A buf1 [32K,64K) B buf0 [64K,96K) B buf1 [96K,128K)
// Tile: 256 rows x 64 bf16 (128 B/row); half = 128 rows = 16 KB.

#define SBAR() __builtin_amdgcn_sched_barrier(0)
#define SGB(m, n) __builtin_amdgcn_sched_group_barrier(m, n, 0)
#define VMW(n) asm volatile("s_waitcnt vmcnt(" #n ")" ::: "memory")
#define LGKM0() asm volatile("s_waitcnt lgkmcnt(0)" ::: "memory")
#define BARRIER() __builtin_amdgcn_s_barrier()
// LLVM SchedGroupMask: MFMA=0x8, DS_READ=0x100

__global__ __launch_bounds__(512, 2) void gemm_bf16_8ph(
    const unsigned short* __restrict__ Agl,  // [M][K] bf16
    const unsigned short* __restrict__ Bgl,  // [N][K] bf16
    float* __restrict__ C) {
    __shared__ alignas(16) unsigned short lds[65536];  // 128 KiB

    const int tid = threadIdx.x;
    const int lane = tid & 63;
    const int wid = tid >> 6;   // 0..7
    const int wr = wid >> 2;    // 0..1 (M sub-block within half)
    const int wc = wid & 3;     // 0..3 (N sub-block within half)

    // T1: XCD swizzle over 1376 = 8*172 blocks.
    const int bid = blockIdx.x;
    const int wg = (bid & 7) * 172 + (bid >> 3);
    const int mt = wg / 43;
    const int nt = wg % 43;
    const int row0 = mt * 256;
    const int col0 = nt * 256;

    // staging lane geometry: wave writes 8 rows x 128 B linear.
    const int r8 = lane >> 3;                // 0..7 == row&7
    const int kc = ((lane & 7) ^ r8) * 8;    // inverse-swizzled global k-elem offset

    // ds_read lane geometry: read row&7 = l15&7.
    const int l15 = lane & 15;
    const int k0o = ((lane >> 4) * 16) ^ ((l15 & 7) << 4);
    const int k1o = k0o ^ 64;
    const int aK0 = (wr * 64 + l15) * 128 + k0o;          // A ds_read bases
    const int aK1 = (wr * 64 + l15) * 128 + k1o;
    const int bK0 = 65536 + (wc * 32 + l15) * 128 + k0o;  // B bases (+64K bias)
    const int bK1 = 65536 + (wc * 32 + l15) * 128 + k1o;
    const char* ldsB = (const char*)lds;
    unsigned short* ldsU = lds;
    const char* AglB = (const char*)Agl;
    const char* BglB = (const char*)Bgl;

    // Persistent 32-bit staging byte-offsets, one per stream [h][i]; +128 B/use.
    uint32_t sA[2][2], sB[2][2];
    #pragma unroll
    for (int h = 0; h < 2; ++h)
        #pragma unroll
        for (int i = 0; i < 2; ++i) {
            sA[h][i] = (uint32_t)(row0 + h * 128 + (wid * 2 + i) * 8 + r8) * (K_ * 2)
                       + (uint32_t)kc * 2;
            sB[h][i] = (uint32_t)(col0 + h * 128 + (wid * 2 + i) * 8 + r8) * (K_ * 2)
                       + (uint32_t)kc * 2;
        }

    auto gA = [&](uint32_t& off, int b, int h, int i) {
        gload16(AglB + off, ldsU + b * 16384 + (h * 128 + (wid * 2 + i) * 8) * 64);
        off += 128;
    };
    auto gB = [&](uint32_t& off, int b, int h, int i) {
        gload16(BglB + off, ldsU + 32768 + b * 16384 + (h * 128 + (wid * 2 + i) * 8) * 64);
        off += 128;
    };

    float4v acc[8][4] = {};
    short8 a0[4][2], a1[4][2];  // A h0/h1 fragments (persist across tiles)
    short8 b0[2][2], b1[2][2];  // B h0/h1 fragments

#define MMA2(MH, NH, I, J, A, B)                                              \
    acc[(MH)*4+(I)][(NH)*2+(J)] = __builtin_amdgcn_mfma_f32_16x16x32_bf16(    \
        A[I][0], B[J][0], acc[(MH)*4+(I)][(NH)*2+(J)], 0, 0, 0);              \
    acc[(MH)*4+(I)][(NH)*2+(J)] = __builtin_amdgcn_mfma_f32_16x16x32_bf16(    \
        A[I][1], B[J][1], acc[(MH)*4+(I)][(NH)*2+(J)], 0, 0, 0);
#define RDA(DST, BASE, I)                                                     \
    DST[I][0] = *(const short8*)(ldsB + (BASE) + (I)*2048 + aK0);             \
    DST[I][1] = *(const short8*)(ldsB + (BASE) + (I)*2048 + aK1);
#define RDB(DST, BASE, J)                                                     \
    DST[J][0] = *(const short8*)(ldsB + (BASE) + (J)*2048 + bK0);             \
    DST[J][1] = *(const short8*)(ldsB + (BASE) + (J)*2048 + bK1);
// SGB pin patterns (counts must match region contents exactly)
#define PIN_32M_8R()                                                          \
    SGB(0x8, 4); SGB(0x100, 1); SGB(0x8, 4); SGB(0x100, 1);                   \
    SGB(0x8, 4); SGB(0x100, 1); SGB(0x8, 4); SGB(0x100, 1);                   \
    SGB(0x8, 4); SGB(0x100, 1); SGB(0x8, 4); SGB(0x100, 1);                   \
    SGB(0x8, 4); SGB(0x100, 1); SGB(0x8, 4); SGB(0x100, 1);
#define PIN_32M_4R()                                                          \
    SGB(0x8, 4); SGB(0x100, 1); SGB(0x8, 4); SGB(0x100, 1);                   \
    SGB(0x8, 4); SGB(0x100, 1); SGB(0x8, 4); SGB(0x100, 1);                   \
    SGB(0x8, 16);
#define PIN_32M()  SGB(0x8, 32);

    // Prologue: tile 0 -> buf0 (A0,A1,B0,B1) + A0(1) -> buf1; VMW(2) leaves
    // the A0(1) pair in flight; read a0,b0 of tile 0.
    gA(sA[0][0], 0, 0, 0); gA(sA[0][1], 0, 0, 1);
    gA(sA[1][0], 0, 1, 0); gA(sA[1][1], 0, 1, 1);
    gB(sB[0][0], 0, 0, 0); gB(sB[0][1], 0, 0, 1);
    gB(sB[1][0], 0, 1, 0); gB(sB[1][1], 0, 1, 1);
    gA(sA[0][0], 1, 0, 0); gA(sA[0][1], 1, 0, 1);  // A0(1) -> buf1, stays in flight
    VMW(2);
    BARRIER(); SBAR();
    RDA(a0, 0, 0) RDA(a0, 0, 1) RDA(a0, 0, 2) RDA(a0, 0, 3)
    RDB(b0, 0, 0) RDB(b0, 0, 1)
    LGKM0(); SBAR();

    // Per tile t (BUF=t&1):
    // P1: stage S1->BUF^1 ; mma<0,0>(a0,b0) ∥ read a1<-BUF      [32M+8R pinned]
    // P2: stage S2->BUF^1 ; mma<1,0>(a1,b0) ∥ read b1<-BUF      [32M+4R]
    // MID: stage S3->BUF ; VMW(MIDW) ; BAR
    // P3: mma<0,1>(a0,b1) ∥ read b0'<-BUF^1 (WAR safe)          [32M+4R]
    // P4: mma<1,1>(a1,b1) ∥ read a0'<-BUF^1                     [32M+8R]
    // END: VMW(ENDW) ; BAR ; lgkmcnt(0)
#define KTILE(BUF, DN, DN2, MIDW, ENDW, DOEND)                                \
    {                                                                         \
        constexpr int CB = (BUF) * 32768;                                     \
        constexpr int NB = ((BUF) ^ 1) * 32768;                               \
        /* ---- P1 ---- */                                                    \
        if (DN) {                                                             \
            gA(sA[1][0], (BUF) ^ 1, 1, 0); gA(sA[1][1], (BUF) ^ 1, 1, 1);     \
            gB(sB[0][0], (BUF) ^ 1, 0, 0); gB(sB[0][1], (BUF) ^ 1, 0, 1);     \
        }                                                                     \
        __builtin_amdgcn_s_setprio(1);                                        \
        MMA2(0, 0, 0, 0, a0, b0) RDA(a1, CB + 16384, 0)                       \
        MMA2(0, 0, 0, 1, a0, b0) RDA(a1, CB + 16384, 1)                       \
        MMA2(0, 0, 1, 0, a0, b0) RDA(a1, CB + 16384, 2)                       \
        MMA2(0, 0, 1, 1, a0, b0) RDA(a1, CB + 16384, 3)                       \
        MMA2(0, 0, 2, 0, a0, b0) MMA2(0, 0, 2, 1, a0, b0)                     \
        MMA2(0, 0, 3, 0, a0, b0) MMA2(0, 0, 3, 1, a0, b0)                     \
        if (DN) { PIN_32M_8R() } else { PIN_32M() }                           \
        __builtin_amdgcn_s_setprio(0);                                        \
        LGKM0(); SBAR();                                                      \
        /* ---- P2 ---- */                                                    \
        if (DN) { gB(sB[1][0], (BUF) ^ 1, 1, 0); gB(sB[1][1], (BUF) ^ 1, 1, 1); } \
        __builtin_amdgcn_s_setprio(1);                                        \
        MMA2(1, 0, 0, 0, a1, b0) RDB(b1, CB + 16384, 0)                       \
        MMA2(1, 0, 0, 1, a1, b0) RDB(b1, CB + 16384, 1)                       \
        MMA2(1, 0, 1, 0, a1, b0) MMA2(1, 0, 1, 1, a1, b0)                     \
        MMA2(1, 0, 2, 0, a1, b0) MMA2(1, 0, 2, 1, a1, b0)                     \
        MMA2(1, 0, 3, 0, a1, b0) MMA2(1, 0, 3, 1, a1, b0)                     \
        PIN_32M_4R()                                                          \
        __builtin_amdgcn_s_setprio(0);                                        \
        LGKM0(); SBAR();                                                      \
        /* ---- MID sync ---- */                                              \
        if (DN2) { gA(sA[0][0], BUF, 0, 0); gA(sA[0][1], BUF, 0, 1); }        \
        VMW(MIDW);                                                            \
        BARRIER(); SBAR();                                                    \
        /* ---- P3 ---- */                                                    \
        __builtin_amdgcn_s_setprio(1);                                        \
        MMA2(0, 1, 0, 0, a0, b1)                                              \
        if (DN) { RDB(b0, NB, 0) }                                            \
        MMA2(0, 1, 0, 1, a0, b1)                                              \
        if (DN) { RDB(b0, NB, 1) }                                            \
        MMA2(0, 1, 1, 0, a0, b1) MMA2(0, 1, 1, 1, a0, b1)                     \
        MMA2(0, 1, 2, 0, a0, b1) MMA2(0, 1, 2, 1, a0, b1)                     \
        MMA2(0, 1, 3, 0, a0, b1) MMA2(0, 1, 3, 1, a0, b1)                     \
        if (DN) { PIN_32M_4R() } else { PIN_32M() }                           \
        __builtin_amdgcn_s_setprio(0);                                        \
        SBAR();                                                               \
        /* ---- P4 ---- */                                                    \
        __builtin_amdgcn_s_setprio(1);                                        \
        MMA2(1, 1, 0, 0, a1, b1)                                              \
        if (DN) { RDA(a0, NB, 0) }                                            \
        MMA2(1, 1, 0, 1, a1, b1)                                              \
        if (DN) { RDA(a0, NB, 1) }                                            \
        MMA2(1, 1, 1, 0, a1, b1)                                              \
        if (DN) { RDA(a0, NB, 2) }                                            \
        MMA2(1, 1, 1, 1, a1, b1)                                              \
        if (DN) { RDA(a0, NB, 3) }                                            \
        MMA2(1, 1, 2, 0, a1, b1) MMA2(1, 1, 2, 1, a1, b1)                     \
        MMA2(1, 1, 3, 0, a1, b1) MMA2(1, 1, 3, 1, a1, b1)                     \
        if (DN) { PIN_32M_8R() } else { PIN_32M() }                           \
        __builtin_amdgcn_s_setprio(0);                                        \
        if (DOEND) {                                                          \
            VMW(ENDW);                                                        \
            BARRIER(); SBAR();                                                \
            LGKM0(); SBAR();                                                  \
        }                                                                     \
    }

    for (int t2 = 0; t2 < NKT - 2; t2 += 2) {
        KTILE(0, 1, 1, 4, 2, 1);
        KTILE(1, 1, 1, 4, 2, 1);
    }
    KTILE(0, 1, 0, 2, 0, 1);  // t=62: no S3; MID drains S3(61)+S1(62); END drains S2(62)
    KTILE(1, 0, 0, 0, 0, 0);  // t=63: pure compute
#undef KTILE
#undef MMA2
#undef RDA
#undef RDB

    // Epilogue: D map col=lane&15, row=(lane>>4)*4+j (m89-verified).
    const int lrow = (lane >> 4) * 4;
    #pragma unroll
    for (int mf = 0; mf < 8; ++mf)
        #pragma unroll
        for (int nf = 0; nf < 4; ++nf)
            #pragma unroll
            for (int j = 0; j < 4; ++j) {
                const int r = row0 + (mf >> 2) * 128 + wr * 64 + (mf & 3) * 16 + lrow + j;
                const int c = col0 + (nf >> 1) * 128 + wc * 32 + (nf & 1) * 16 + l15;
                C[(size_t)r * N_ + c] = acc[mf][nf][j];
            }
}

// ---------------- Fallback: round-1 fused kernel ----------------
static constexpr int LDSS = 40;

__global__ __launch_bounds__(256, 2) void w4_gemm_fused(
    const float* __restrict__ X, const int* __restrict__ Q,
    const float* __restrict__ SZ, float* __restrict__ C) {
    __shared__ alignas(16) unsigned short As[128 * LDSS];
    __shared__ alignas(16) unsigned short Ws[128 * LDSS];
    const int tid = threadIdx.x;
    const int lane = tid & 63;
    const int wid = tid >> 6;
    const int wrr = wid >> 1;
    const int wcc = wid & 1;
    const int row0 = blockIdx.x * 128;
    const int col0 = blockIdx.y * 128;
    float4v acc[4][4] = {};
    float4v a_reg[4];
    int4v q_reg[4];
    float2v sz_reg[4];

    auto load_tile = [&](int kb) {
        const int g = kb >> 7;
        #pragma unroll
        for (int i = 0; i < 4; ++i) {
            const int idx = tid + 256 * i;
            const int r = idx >> 3;
            const int v = idx & 7;
            a_reg[i] = *(const float4v*)(X + (size_t)(row0 + r) * K_ + kb + v * 4);
            q_reg[i] = *(const int4v*)(Q + (size_t)(col0 + r) * K_ + kb + v * 4);
            sz_reg[i] = *(const float2v*)(SZ + ((size_t)g * N_ + (col0 + r)) * 2);
        }
    };
    auto write_tile = [&]() {
        #pragma unroll
        for (int i = 0; i < 4; ++i) {
            const int idx = tid + 256 * i;
            const int r = idx >> 3;
            const int v = idx & 7;
            ushort4v ab, wb;
            #pragma unroll
            for (int j = 0; j < 4; ++j) ab[j] = f2bf(a_reg[i][j]);
            const float s = sz_reg[i][0];
            const float z = sz_reg[i][1];
            #pragma unroll
            for (int j = 0; j < 4; ++j) wb[j] = f2bf((float)(q_reg[i][j] - 8) * s + z);
            *(ushort4v*)(&As[r * LDSS + v * 4]) = ab;
            *(ushort4v*)(&Ws[r * LDSS + v * 4]) = wb;
        }
    };
    auto compute = [&]() {
        const int lr = lane & 15;
        const int lg = lane >> 4;
        short8 af[4], bf[4];
        #pragma unroll
        for (int mf = 0; mf < 4; ++mf)
            af[mf] = *(const short8*)(&As[(wrr * 64 + mf * 16 + lr) * LDSS + lg * 8]);
        #pragma unroll
        for (int nf = 0; nf < 4; ++nf)
            bf[nf] = *(const short8*)(&Ws[(wcc * 64 + nf * 16 + lr) * LDSS + lg * 8]);
        #pragma unroll
        for (int mf = 0; mf < 4; ++mf)
            #pragma unroll
            for (int nf = 0; nf < 4; ++nf)
                acc[mf][nf] = __builtin_amdgcn_mfma_f32_16x16x32_bf16(
                    af[mf], bf[nf], acc[mf][nf], 0, 0, 0);
    };

    load_tile(0);
    for (int kb = 0; kb < K_; kb += 32) {
        __syncthreads();
        write_tile();
        __syncthreads();
        if (kb + 32 < K_) load_tile(kb + 32);
        compute();
    }
    const int lr = lane & 15;
    const int lg = lane >> 4;
    #pragma unroll
    for (int mf = 0; mf < 4; ++mf)
        #pragma unroll
        for (int nf = 0; nf < 4; ++nf)
            #pragma unroll
            for (int j = 0; j < 4; ++j) {
                const int r = row0 + wrr * 64 + mf * 16 + lg * 4 + j;
                const int c = col0 + wcc * 64 + nf * 16 + lr;
                C[(size_t)r * N_ + c] = acc[mf][nf][j];
            }
}

extern "C" void kernel_launch(void* const* d_in, const int* in_sizes, int n_in,
                              void* d_out, int out_size, void* d_ws, size_t ws_size,
                              hipStream_t stream) {
    const float* X  = (const float*)d_in[0];
    const int*   Q  = (const int*)d_in[1];
    const float* SZ = (const float*)d_in[2];
    float* C = (float*)d_out;

    const size_t xb_bytes = (size_t)M_ * K_ * 2;
    const size_t wb_bytes = (size_t)N_ * K_ * 2;
    if (ws_size >= xb_bytes + wb_bytes) {
        unsigned short* Xb = (unsigned short*)d_ws;
        unsigned short* Wb = (unsigned short*)((char*)d_ws + xb_bytes);
        cvt_x_kernel<<<(M_ * (K_ / 8)) / 256, 256, 0, stream>>>(X, Xb);
        deq_w_kernel<<<(N_ * (K_ / 8)) / 256, 256, 0, stream>>>(Q, SZ, Wb);
        gemm_bf16_8ph<<<dim3(1376), dim3(512), 0, stream>>>(Xb, Wb, C);
    } else {
        dim3 grid(M_ / 128, N_ / 128);
        w4_gemm_fused<<<grid, dim3(256), 0, stream>>>(X, Q, SZ, C);
    }
}